// Round 9
// baseline (2008.318 us; speedup 1.0000x reference)
//
#include <hip/hip_runtime.h>
#include <hip/hip_bf16.h>
#include <math.h>

#define B_SZ   16384
#define IN_SZ  512
#define CH_SZ  1024
#define ED_SZ  4096
#define NC_SZ  8
#define NE_SZ  512
#define D_SZ   512

typedef short short8 __attribute__((ext_vector_type(8)));
typedef float f32x4 __attribute__((ext_vector_type(4)));

__device__ __forceinline__ ushort f2bf(float f) {
  union { float f; unsigned u; } v; v.f = f;
  unsigned u = v.u;
  return (ushort)((u + 0x7fffu + ((u >> 16) & 1u)) >> 16);  // RNE
}
__device__ __forceinline__ float bf2f(ushort h) {
  union { unsigned u; float f; } v; v.u = ((unsigned)h) << 16; return v.f;
}

__device__ __forceinline__ void gload_lds16(const void* g, void* l) {
  __builtin_amdgcn_global_load_lds(
      (const __attribute__((address_space(1))) void*)g,
      (__attribute__((address_space(3))) void*)l, 16, 0, 0);
}

#define WAITV(N) asm volatile("s_waitcnt vmcnt(" #N ")" ::: "memory")
#define WAITL()  asm volatile("s_waitcnt lgkmcnt(0)" ::: "memory")
#define BAR()    asm volatile("s_barrier" ::: "memory")
#define SP1()    __builtin_amdgcn_s_setprio(1)
#define SP0()    __builtin_amdgcn_s_setprio(0)

// ===================== fused z + dist kernel (v4: Z stays in LDS) =========
// grid 1024 = (B/128) x NC; c = bid&7 (XCD-pinned Wq/embT slices).
// LDS 160 KB (1 block/CU): phase 1 uses [0:120KB) as 3-deep A+B staging;
// phase 2 overwrites [0:128KB) with Z bf16 (swizzled); phase 3 stages embT
// in 2x16KB half-tiles at [128:160KB), A-frags read from Z-LDS.
// No zG global bounce: WRITE drops ~164 MB vs v3.
__global__ __launch_bounds__(512, 1) void k_zdist(
    const ushort* __restrict__ preB, const ushort* __restrict__ WqB,
    const float* __restrict__ bq, const ushort* __restrict__ embT,
    const float* __restrict__ esq, float* __restrict__ zzG,
    unsigned long long* __restrict__ amin)
{
  __shared__ ushort smem[81920];                 // 163840 B = 160 KB
  const int tid = threadIdx.x;
  const int lane = tid & 63;
  const int w = tid >> 6;
  const int wm = w >> 2, wn = w & 3;             // 2M x 4N waves
  const int g = lane >> 4, c0 = lane & 15;
  const int bid = blockIdx.x;
  const int c = bid & 7;
  const int mBase = (bid >> 3) * 128;

  // phase-1 staging sources (pre-swizzled cols, linear LDS dest)
  const int arow = tid >> 2, aslot = tid & 3;
  const int acs = (aslot ^ (arow & 3)) * 8;
  const ushort* aSrcP = preB + (size_t)(mBase + arow)*CH_SZ + acs;
  const ushort* bSrcW[4];
  #pragma unroll
  for (int j = 0; j < 4; ++j) {
    int q = tid + j*512, br = q >> 2, bs = ((q & 3) ^ (br & 3)) * 8;
    bSrcW[j] = WqB + (size_t)(c*512 + br)*CH_SZ + bs;
  }
  // phase-3 embT staging: half = 256 ne-rows x 32 k = 16 KB; 2 chunks/thread
  const ushort* eSrc[2];
  #pragma unroll
  for (int j = 0; j < 2; ++j) {
    int f = tid + j*512, er = f >> 2, es = ((f & 3) ^ (er & 3)) * 8;
    eSrc[j] = embT + (size_t)(c*512 + er)*512 + es;   // er in [0,256)
  }

  // ---------------- phase 1: z-GEMM (K=1024, 32 tiles, 3-deep) -----------
  f32x4 acc[4][8];
  #pragma unroll
  for (int m=0;m<4;++m)
    #pragma unroll
    for (int n=0;n<8;++n) acc[m][n] = (f32x4){0.f,0.f,0.f,0.f};

  {
    auto issue = [&](int t) {
      int kt = t * 32, b = t % 3;
      ushort* ab = smem + b*20480;
      ushort* bb = smem + b*20480 + 4096;
      gload_lds16(aSrcP + kt, ab + tid*8);
      #pragma unroll
      for (int j=0;j<4;++j) gload_lds16(bSrcW[j] + kt, bb + (tid + j*512)*8);
    };
    issue(0); issue(1);                          // 10 outstanding
    for (int t = 0; t < 32; ++t) {
      if (t < 31) { WAITV(5); } else { WAITV(0); }
      BAR();                                     // tile t visible to all
      if (t + 2 < 32) issue(t + 2);              // overwrites buf of t-1 (safe)
      const ushort* ab = smem + (t % 3)*20480;
      const ushort* bb = ab + 4096;
      short8 af[4], bf2[8];
      #pragma unroll
      for (int m=0;m<4;++m) {
        int ar = wm*64 + m*16 + c0;
        af[m] = *(const short8*)(ab + ar*32 + ((g ^ (ar & 3)) * 8));
      }
      #pragma unroll
      for (int n=0;n<8;++n) {
        int br = wn*128 + n*16 + c0;
        bf2[n] = *(const short8*)(bb + br*32 + ((g ^ (br & 3)) * 8));
      }
      SP1();
      #pragma unroll
      for (int m=0;m<4;++m)
        #pragma unroll
        for (int n=0;n<8;++n)
          acc[m][n] = __builtin_amdgcn_mfma_f32_16x16x32_bf16(af[m], bf2[n], acc[m][n], 0, 0, 0);
      SP0();
    }
    BAR();                                       // all phase-1 LDS reads done
  }

  // ---------------- phase 2: acc -> Z bf16 in LDS (swizzled) + norms -----
  #pragma unroll
  for (int m=0;m<4;++m) {
    float sq[4] = {0.f,0.f,0.f,0.f};
    #pragma unroll
    for (int n=0;n<8;++n) {
      int col = wn*128 + n*16 + c0;
      float bb = bq[c*512 + col];
      #pragma unroll
      for (int r=0;r<4;++r) {
        int row = wm*64 + m*16 + g*4 + r;
        float v = acc[m][n][r] + bb;
        ushort hb = f2bf(v);
        int byte = row*1024 + ((col*2) ^ ((row&7)<<4));
        smem[byte>>1] = hb;
        float vb = bf2f(hb);
        sq[r] += vb*vb;
      }
    }
    #pragma unroll
    for (int r=0;r<4;++r) {
      float s = sq[r];
      s += __shfl_xor(s,1); s += __shfl_xor(s,2);
      s += __shfl_xor(s,4); s += __shfl_xor(s,8);
      if (c0 == 0) {
        int row = wm*64 + m*16 + g*4 + r;
        atomicAdd(&zzG[(size_t)(mBase + row)*NC_SZ + c], s);
      }
    }
  }
  WAITL();                                       // drain Z ds_writes
  BAR();                                         // Z published

  // ---------------- phase 3: dist GEMM from Z-LDS ------------------------
  // 32 stages s = kt*2 + half; embT half staged into 2x16KB ping-pong.
  f32x4 acc2[4][8];
  #pragma unroll
  for (int m=0;m<4;++m)
    #pragma unroll
    for (int n=0;n<8;++n) acc2[m][n] = (f32x4){0.f,0.f,0.f,0.f};

  {
    auto issue_e = [&](int s) {
      int kt = (s >> 1) * 32, h = s & 1;
      ushort* eb = smem + 65536 + h*8192;
      #pragma unroll
      for (int j=0;j<2;++j)
        gload_lds16(eSrc[j] + (size_t)h*256*512 + kt, eb + (tid + j*512)*8);
    };
    issue_e(0); issue_e(1);                      // 4 outstanding
    for (int s = 0; s < 32; ++s) {
      if (s < 31) { WAITV(2); } else { WAITV(0); }
      BAR();                                     // half s visible
      const int kt = s >> 1, h = s & 1;
      const ushort* eb = smem + 65536 + h*8192;
      short8 af[4], bf2[4];
      #pragma unroll
      for (int m=0;m<4;++m) {
        int ar = wm*64 + m*16 + c0;
        af[m] = *(const short8*)(smem + ((ar*1024 + ((kt*64 + g*16) ^ ((ar&7)<<4)))>>1));
      }
      #pragma unroll
      for (int n=0;n<4;++n) {
        int rbr = wn*64 + n*16 + c0;             // row within half
        bf2[n] = *(const short8*)(eb + ((rbr*64 + ((g*16) ^ ((rbr&3)<<4)))>>1));
      }
      SP1();
      #pragma unroll
      for (int m=0;m<4;++m)
        #pragma unroll
        for (int n=0;n<4;++n)
          acc2[m][h*4+n] = __builtin_amdgcn_mfma_f32_16x16x32_bf16(af[m], bf2[n], acc2[m][h*4+n], 0, 0, 0);
      SP0();
      BAR();                                     // all done reading buf h
      if (s + 2 < 32) issue_e(s + 2);            // safe to overwrite buf h
    }
  }

  // epilogue: fold (min,idx) over j and c0, publish via u64 atomicMin
  #pragma unroll
  for (int m=0;m<4;++m) {
    float rv[4]; int ri[4];
    #pragma unroll
    for (int r=0;r<4;++r) { rv[r] = 3.0e38f; ri[r] = 0; }
    #pragma unroll
    for (int j=0;j<8;++j) {
      int ne = (j>>2)*256 + wn*64 + (j&3)*16 + c0;
      float ev = esq[c*512 + ne];
      #pragma unroll
      for (int r=0;r<4;++r) {
        float v = ev - 2.0f*acc2[m][j][r];
        if (v < rv[r]) { rv[r] = v; ri[r] = ne; }
      }
    }
    #pragma unroll
    for (int r=0;r<4;++r) {
      float bv = rv[r]; int bi = ri[r];
      #pragma unroll
      for (int off=1; off<16; off<<=1) {
        float ov = __shfl_xor(bv, off);
        int   oi = __shfl_xor(bi, off);
        if (ov < bv || (ov == bv && oi < bi)) { bv = ov; bi = oi; }
      }
      if (c0 == 0) {
        unsigned u; { union {float f; unsigned uu;} cv; cv.f = bv; u = cv.uu; }
        unsigned k = (u & 0x80000000u) ? ~u : (u | 0x80000000u);
        unsigned long long key = (((unsigned long long)k) << 32) | (unsigned)bi;
        int row = wm*64 + m*16 + g*4 + r;
        atomicMin(&amin[(size_t)(mBase + row)*NC_SZ + c], key);
      }
    }
  }
}

// unpack argmin winners -> counts + dacc
__global__ __launch_bounds__(256) void k_fin2(
    const unsigned long long* __restrict__ amin, const float* __restrict__ zzG,
    int* __restrict__ counts, float* __restrict__ dacc)
{
  int t = blockIdx.x*256 + threadIdx.x;          // t < B*NC
  unsigned long long key = amin[t];
  unsigned k = (unsigned)(key >> 32);
  int ne = (int)(key & 0xFFFFFFFFu);
  unsigned u = (k & 0x80000000u) ? (k ^ 0x80000000u) : ~k;
  float bv; { union {unsigned uu; float f;} cv; cv.uu = u; bv = cv.f; }
  int c = t & 7;
  atomicAdd(&counts[c*NE_SZ + ne], 1);
  float dm = bv + zzG[t];
  #pragma unroll
  for (int off=1; off<64; off<<=1) dm += __shfl_xor(dm, off);
  if ((threadIdx.x & 63) == 0) atomicAdd(dacc, dm);
}

// ===================== 256x256 GEMM core =====================
#define RD_A(P) _Pragma("unroll") for (int m=0;m<4;++m){ int ar=wm*64+m*16+c0; int sw=(ar&7)<<4; \
  _Pragma("unroll") for (int ks=0;ks<2;++ks) af[m][ks]=*(const short8*)((P)+ar*64+((((ks<<6)|gsh)^sw)>>1)); }
#define RD_B_H(H,P) _Pragma("unroll") for (int n=0;n<2;++n){ int br=wn*32+n*16+c0; int sw=(br&7)<<4; \
  _Pragma("unroll") for (int ks=0;ks<2;++ks) bfr[H][n][ks]=*(const short8*)((P)+br*64+((((ks<<6)|gsh)^sw)>>1)); }
#define MM(HA,HB) _Pragma("unroll") for (int m=0;m<4;++m) _Pragma("unroll") for (int n=0;n<2;++n){ \
  acc[HA][m][HB][n]=__builtin_amdgcn_mfma_f32_16x16x32_bf16(af[m][0],bfr[HB][n][0],acc[HA][m][HB][n],0,0,0); \
  acc[HA][m][HB][n]=__builtin_amdgcn_mfma_f32_16x16x32_bf16(af[m][1],bfr[HB][n][1],acc[HA][m][HB][n],0,0,0); }

template<int NT>
__device__ __forceinline__ void gemm256(
    const ushort* __restrict__ A, int lda, int aBase,
    const ushort* __restrict__ Bt, int ldb, int bBase,
    ushort* sA, ushort* sB, f32x4 (&acc)[2][4][2][2])
{
  const int tid = threadIdx.x;
  const int lane = tid & 63;
  const int w = tid >> 6;
  const int wm = w >> 2, wn = w & 3;
  const int g = lane >> 4, c0 = lane & 15;
  const int gsh = g << 4;

  const int f0 = tid, f1 = 512 + tid;
  const int r0 = f0 >> 3, r1 = f1 >> 3;
  const int cs0 = ((f0 & 7) ^ (r0 & 7)) * 8, cs1 = ((f1 & 7) ^ (r1 & 7)) * 8;
  const ushort* aS0 = A + (size_t)(aBase + r0)*lda + cs0;
  const ushort* aS1 = A + (size_t)(aBase + r1)*lda + cs1;
  const ushort* bS0 = Bt + (size_t)(bBase + r0)*ldb + cs0;
  const ushort* bS1 = Bt + (size_t)(bBase + r1)*ldb + cs1;
  const size_t a128 = (size_t)128*lda, b128 = (size_t)128*ldb;

  auto issue = [&](int si) {
    int tt = si >> 2, q = si & 3, kt = tt << 6, buf2 = (tt & 1) * 2;
    if (q == 0)      { ushort* d = sA +  buf2   *8192; gload_lds16(aS0 + kt,        d + f0*8); gload_lds16(aS1 + kt,        d + f1*8); }
    else if (q == 1) { ushort* d = sB +  buf2   *8192; gload_lds16(bS0 + kt,        d + f0*8); gload_lds16(bS1 + kt,        d + f1*8); }
    else if (q == 2) { ushort* d = sB + (buf2+1)*8192; gload_lds16(bS0 + b128 + kt, d + f0*8); gload_lds16(bS1 + b128 + kt, d + f1*8); }
    else             { ushort* d = sA + (buf2+1)*8192; gload_lds16(aS0 + a128 + kt, d + f0*8); gload_lds16(aS1 + a128 + kt, d + f1*8); }
  };

  #pragma unroll
  for (int hA=0;hA<2;++hA)
    #pragma unroll
    for (int m=0;m<4;++m)
      #pragma unroll
      for (int hB=0;hB<2;++hB)
        #pragma unroll
        for (int n=0;n<2;++n) acc[hA][m][hB][n] = (f32x4){0.f,0.f,0.f,0.f};

  issue(0); issue(1); issue(2); issue(3);
  WAITV(2); BAR();

  for (int t = 0; t < NT-1; ++t) {
    const int buf2 = (t & 1) * 2;
    const ushort* pA0 = sA +  buf2   *8192;
    const ushort* pA1 = sA + (buf2+1)*8192;
    const ushort* pB0 = sB +  buf2   *8192;
    const ushort* pB1 = sB + (buf2+1)*8192;
    short8 af[4][2], bfr[2][2][2];
    RD_A(pA0); RD_B_H(0,pB0); RD_B_H(1,pB1);
    issue(4*t+4);
    SP1(); MM(0,0); SP0();
    issue(4*t+5); issue(4*t+6);
    WAITV(6);
    SP1(); MM(0,1); SP0();
    BAR();
    RD_A(pA1);
    SP1(); MM(1,0); SP0();
    issue(4*t+7);
    WAITV(2);
    SP1(); MM(1,1); SP0();
    BAR();
  }
  {
    const int buf2 = ((NT-1) & 1) * 2;
    const ushort* pA0 = sA +  buf2   *8192;
    const ushort* pA1 = sA + (buf2+1)*8192;
    const ushort* pB0 = sB +  buf2   *8192;
    const ushort* pB1 = sB + (buf2+1)*8192;
    short8 af[4][2], bfr[2][2][2];
    RD_A(pA0); RD_B_H(0,pB0); RD_B_H(1,pB1);
    SP1(); MM(0,0); SP0();
    WAITV(0);
    SP1(); MM(0,1); SP0();
    BAR();
    RD_A(pA1);
    SP1(); MM(1,0); MM(1,1); SP0();
  }
}

// concat x-GEMM: pre | h1 in one GEMM (N=2048), grid 512, XCD-pinned n-slice
__global__ __launch_bounds__(512, 2) void k256_xcat(
    const ushort* __restrict__ A, const ushort* __restrict__ Wcat,
    const float* __restrict__ b_f, const float* __restrict__ b_x1,
    ushort* __restrict__ pre, ushort* __restrict__ h1)
{
  __shared__ ushort smem[65536];
  ushort* sA = smem;
  ushort* sB = smem + 32768;
  f32x4 acc[2][4][2][2];
  const int bid = blockIdx.x;
  const int nBase = (bid & 7) * 256;
  const int mBase = (bid >> 3) * 256;
  gemm256<8>(A, IN_SZ, mBase, Wcat, IN_SZ, nBase, sA, sB, acc);
  const int lane = threadIdx.x & 63, w = threadIdx.x >> 6;
  const int wm = w >> 2, wn = w & 3, g = lane >> 4, c0 = lane & 15;
  const int side = nBase >> 10;                  // 0: pre, 1: h1
  ushort* Cout = side ? h1 : pre;
  const float* bias = side ? b_x1 : b_f;
  const int obase = nBase & 1023;
  __syncthreads();
  #pragma unroll
  for (int hA=0;hA<2;++hA)
    #pragma unroll
    for (int m=0;m<4;++m)
      #pragma unroll
      for (int hB=0;hB<2;++hB)
        #pragma unroll
        for (int n=0;n<2;++n) {
          int lcol = hB*128 + wn*32 + n*16 + c0;
          float bb = bias[obase + lcol];
          #pragma unroll
          for (int r=0;r<4;++r) {
            int lrow = hA*128 + wm*64 + m*16 + g*4 + r;
            smem[lrow*256 + lcol] = f2bf(fmaxf(acc[hA][m][hB][n][r] + bb, 0.f));
          }
        }
  __syncthreads();
  #pragma unroll
  for (int p=0;p<16;++p) {
    int row = p*16 + (threadIdx.x >> 5);
    short8 v = *(const short8*)(smem + row*256 + (threadIdx.x & 31)*8);
    *(short8*)(Cout + (size_t)(mBase + row)*CH_SZ + obase + (threadIdx.x & 31)*8) = v;
  }
}

// ===================== small kernels =====================
template<int BM, int BN>
__device__ __forceinline__ void gemm_core(
    const ushort* __restrict__ A, int lda, int aBase,
    const ushort* __restrict__ Bt, int ldb, int bBase,
    int K,
    ushort (&sA)[BM][64], ushort (&sB)[BN][64],
    f32x4 (&acc)[BM/32][BN/32])
{
  constexpr int MF = BM/32, NF = BN/32;
  const int tid = threadIdx.x;
  const int lane = tid & 63;
  const int w = tid >> 6;
  const int g = lane >> 4, c0 = lane & 15;
  const int wrow = (w >> 1) * (BM/2), wcol = (w & 1) * (BN/2);

  #pragma unroll
  for (int m=0;m<MF;m++)
    #pragma unroll
    for (int n=0;n<NF;n++) acc[m][n] = (f32x4){0.f,0.f,0.f,0.f};

  for (int kt = 0; kt < K; kt += 64) {
    #pragma unroll
    for (int i = 0; i < BM/32; ++i) {
      int f = i*256 + tid;
      int r = f >> 3, cc = f & 7;
      gload_lds16(A + (size_t)(aBase + r)*lda + (kt + cc*8), &sA[r][cc*8]);
    }
    #pragma unroll
    for (int i = 0; i < BN/32; ++i) {
      int f = i*256 + tid;
      int r = f >> 3, cc = f & 7;
      gload_lds16(Bt + (size_t)(bBase + r)*ldb + (kt + cc*8), &sB[r][cc*8]);
    }
    __syncthreads();
    #pragma unroll
    for (int ks = 0; ks < 64; ks += 32) {
      short8 av[MF], bv2[NF];
      #pragma unroll
      for (int m=0;m<MF;m++)
        av[m] = *(const short8*)(&sA[wrow + m*16 + c0][ks + g*8]);
      #pragma unroll
      for (int n=0;n<NF;n++)
        bv2[n] = *(const short8*)(&sB[wcol + n*16 + c0][ks + g*8]);
      #pragma unroll
      for (int m=0;m<MF;m++)
        #pragma unroll
        for (int n=0;n<NF;n++)
          acc[m][n] = __builtin_amdgcn_mfma_f32_16x16x32_bf16(av[m], bv2[n], acc[m][n], 0, 0, 0);
    }
    __syncthreads();
  }
}

__global__ __launch_bounds__(256) void k_cvt(const float* __restrict__ s,
                                             ushort* __restrict__ d, int n) {
  int i = (blockIdx.x*256 + threadIdx.x)*4;
  if (i + 3 < n) {
    float4 v = *(const float4*)(s + i);
    ushort4 o;
    o.x = f2bf(v.x); o.y = f2bf(v.y); o.z = f2bf(v.z); o.w = f2bf(v.w);
    *(ushort4*)(d + i) = o;
  }
}

__global__ __launch_bounds__(256) void k_pad_wx2(const float* __restrict__ s,
                                                 ushort* __restrict__ d) {
  int i = blockIdx.x*256 + threadIdx.x;
  int row = i >> 10, col = i & 1023;
  d[i] = (row < 63) ? f2bf(s[row*1024 + col]) : (ushort)0;
}

__global__ void k_embT(const float* __restrict__ embed,
                       ushort* __restrict__ embT, float* __restrict__ e_sq) {
  __shared__ float t[32][33];
  int c = blockIdx.x, d0 = blockIdx.y*32, n0 = blockIdx.z*32;
  const float* src = embed + ((size_t)c*D_SZ + d0)*NE_SZ + n0;
  for (int dy = threadIdx.y; dy < 32; dy += 8)
    t[dy][threadIdx.x] = src[(size_t)dy*NE_SZ + threadIdx.x];
  __syncthreads();
  ushort* dst = embT + ((size_t)c*NE_SZ + n0)*D_SZ + d0;
  for (int ny = threadIdx.y; ny < 32; ny += 8)
    dst[(size_t)ny*D_SZ + threadIdx.x] = f2bf(t[threadIdx.x][ny]);
  if (threadIdx.y == 0) {
    float s = 0.f;
    #pragma unroll
    for (int dd = 0; dd < 32; ++dd) { float v = t[dd][threadIdx.x]; s += v*v; }
    atomicAdd(&e_sq[c*NE_SZ + n0 + threadIdx.x], s);
  }
}

__global__ __launch_bounds__(256) void k_gemm_dec(
    const ushort* __restrict__ H1, const ushort* __restrict__ Wx2b,
    const float* __restrict__ b_x2, const float* __restrict__ Wd1,
    const float* __restrict__ bd1, const float* __restrict__ Wd2,
    const float* __restrict__ bd2, float* __restrict__ dec)
{
  __shared__ ushort sA[64][64], sB[64][64];
  __shared__ float semb[64][65];
  f32x4 acc[2][2];
  int mBase = blockIdx.x*64;
  gemm_core<64,64>(H1, CH_SZ, mBase, Wx2b, CH_SZ, 0, CH_SZ, sA, sB, acc);
  int lane = threadIdx.x&63, w = threadIdx.x>>6;
  int g = lane>>4, c0 = lane&15, wrow = (w>>1)*32, wcol = (w&1)*32;
  #pragma unroll
  for (int m=0;m<2;m++)
    #pragma unroll
    for (int n=0;n<2;n++) {
      int col = wcol + n*16 + c0;
      float bb = (col < 63) ? b_x2[col] : 0.f;
      #pragma unroll
      for (int r=0;r<4;r++)
        semb[wrow + m*16 + g*4 + r][col] = acc[m][n][r] + bb;
    }
  __syncthreads();
  if (threadIdx.x < 64) {
    int lrow = threadIdx.x;
    float o = bd2[0];
    for (int j=0;j<63;++j) {
      float s = bd1[j];
      #pragma unroll 7
      for (int i=0;i<63;++i) s += semb[lrow][i]*Wd1[j*63+i];
      o += fmaxf(s, 0.f)*Wd2[j];
    }
    dec[mBase + lrow] = o;
  }
}

__global__ __launch_bounds__(256) void k_final(const int* __restrict__ counts,
                                               const float* __restrict__ dacc,
                                               float* __restrict__ out) {
  double s = 0.0;
  for (int i = threadIdx.x; i < NC_SZ*NE_SZ; i += 256) {
    double p = (double)counts[i] / (double)B_SZ;
    s -= p * log(p + 1e-10);
  }
  #pragma unroll
  for (int off=1; off<64; off<<=1) s += __shfl_xor(s, off);
  __shared__ double wsum[4];
  if ((threadIdx.x&63) == 0) wsum[threadIdx.x>>6] = s;
  __syncthreads();
  if (threadIdx.x == 0) {
    double e = wsum[0]+wsum[1]+wsum[2]+wsum[3];
    out[B_SZ]   = (float)((double)dacc[0] / ((double)B_SZ * (double)D_SZ));
    out[B_SZ+1] = (float)exp(e);
  }
}

extern "C" void kernel_launch(void* const* d_in, const int* in_sizes, int n_in,
                              void* d_out, int out_size, void* d_ws, size_t ws_size,
                              hipStream_t stream) {
  (void)in_sizes; (void)n_in; (void)out_size; (void)ws_size;
  const float* x    = (const float*)d_in[0];
  const float* W_f  = (const float*)d_in[1];
  const float* b_f  = (const float*)d_in[2];
  const float* W_x1 = (const float*)d_in[3];
  const float* b_x1 = (const float*)d_in[4];
  const float* W_x2 = (const float*)d_in[5];
  const float* b_x2 = (const float*)d_in[6];
  const float* Wq   = (const float*)d_in[7];
  const float* bq   = (const float*)d_in[8];
  const float* Wd1  = (const float*)d_in[9];
  const float* bd1  = (const float*)d_in[10];
  const float* Wd2  = (const float*)d_in[11];
  const float* bd2  = (const float*)d_in[12];
  const float* embed= (const float*)d_in[13];
  float* out = (float*)d_out;

  char* ws = (char*)d_ws;
  size_t off = 0;
  auto alloc = [&](size_t bytes) {
    void* p = ws + off; off = (off + bytes + 255) & ~(size_t)255; return p;
  };
  ushort* xb    = (ushort*)alloc((size_t)B_SZ*IN_SZ*2);
  ushort* preb  = (ushort*)alloc((size_t)B_SZ*CH_SZ*2);
  ushort* h1b   = (ushort*)alloc((size_t)B_SZ*CH_SZ*2);
  ushort* wcat  = (ushort*)alloc((size_t)2*CH_SZ*IN_SZ*2);
  ushort* wqb   = (ushort*)alloc((size_t)ED_SZ*CH_SZ*2);
  ushort* wx2b  = (ushort*)alloc((size_t)64*CH_SZ*2);
  ushort* embTb = (ushort*)alloc((size_t)NC_SZ*NE_SZ*D_SZ*2);
  float*  esq   = (float*)alloc((size_t)NC_SZ*NE_SZ*4);
  float*  zzG   = (float*)alloc((size_t)B_SZ*NC_SZ*4);
  unsigned long long* amin = (unsigned long long*)alloc((size_t)B_SZ*NC_SZ*8);
  int*    counts= (int*)alloc(4096*4);
  float*  dacc  = (float*)alloc(256);

  hipMemsetAsync(esq, 0, (size_t)NC_SZ*NE_SZ*4, stream);
  hipMemsetAsync(zzG, 0, (size_t)B_SZ*NC_SZ*4, stream);
  hipMemsetAsync(amin, 0xFF, (size_t)B_SZ*NC_SZ*8, stream);
  hipMemsetAsync(counts, 0, 4096*4, stream);
  hipMemsetAsync(dacc, 0, 4, stream);

  k_cvt<<<(B_SZ*IN_SZ/4+255)/256, 256, 0, stream>>>(x, xb, B_SZ*IN_SZ);
  k_cvt<<<(CH_SZ*IN_SZ/4+255)/256, 256, 0, stream>>>(W_f, wcat, CH_SZ*IN_SZ);
  k_cvt<<<(CH_SZ*IN_SZ/4+255)/256, 256, 0, stream>>>(W_x1, wcat + (size_t)CH_SZ*IN_SZ, CH_SZ*IN_SZ);
  k_cvt<<<(ED_SZ*CH_SZ/4+255)/256, 256, 0, stream>>>(Wq, wqb, ED_SZ*CH_SZ);
  k_pad_wx2<<<(64*CH_SZ)/256, 256, 0, stream>>>(W_x2, wx2b);
  k_embT<<<dim3(NC_SZ, D_SZ/32, NE_SZ/32), dim3(32,8), 0, stream>>>(embed, embTb, esq);

  // pre = relu(x@W_f^T+b_f), h1 = relu(x@W_x1^T+b_x1) in ONE GEMM (N=2048)
  k256_xcat<<<(B_SZ/256)*8, 512, 0, stream>>>(xb, wcat, b_f, b_x1, preb, h1b);
  // fused z-GEMM + dist, Z kept in LDS (no global bounce)
  k_zdist<<<(B_SZ/128)*NC_SZ, 512, 0, stream>>>(
      preb, wqb, bq, embTb, esq, zzG, amin);
  // emb = h1 @ W_x2^T + b_x2 ; dec = decoder(emb)
  k_gemm_dec<<<dim3(B_SZ/64), 256, 0, stream>>>(h1b, wx2b, b_x2, Wd1, bd1, Wd2, bd2, out);
  k_fin2<<<(B_SZ*NC_SZ)/256, 256, 0, stream>>>(amin, zzG, counts, dacc);
  k_final<<<1, 256, 0, stream>>>(counts, dacc, out);
}

// Round 10
// 596.781 us; speedup vs baseline: 3.3653x; 3.3653x over previous
//
#include <hip/hip_runtime.h>
#include <hip/hip_bf16.h>
#include <math.h>

#define B_SZ   16384
#define IN_SZ  512
#define CH_SZ  1024
#define ED_SZ  4096
#define NC_SZ  8
#define NE_SZ  512
#define D_SZ   512

typedef short short8 __attribute__((ext_vector_type(8)));
typedef float f32x4 __attribute__((ext_vector_type(4)));

__device__ __forceinline__ ushort f2bf(float f) {
  union { float f; unsigned u; } v; v.f = f;
  unsigned u = v.u;
  return (ushort)((u + 0x7fffu + ((u >> 16) & 1u)) >> 16);  // RNE
}
__device__ __forceinline__ float bf2f(ushort h) {
  union { unsigned u; float f; } v; v.u = ((unsigned)h) << 16; return v.f;
}

__device__ __forceinline__ void gload_lds16(const void* g, void* l) {
  __builtin_amdgcn_global_load_lds(
      (const __attribute__((address_space(1))) void*)g,
      (__attribute__((address_space(3))) void*)l, 16, 0, 0);
}

#define WAITV(N) asm volatile("s_waitcnt vmcnt(" #N ")" ::: "memory")
#define WAITL()  asm volatile("s_waitcnt lgkmcnt(0)" ::: "memory")
#define BAR()    asm volatile("s_barrier" ::: "memory")
#define SP1()    __builtin_amdgcn_s_setprio(1)
#define SP0()    __builtin_amdgcn_s_setprio(0)

// ===================== fused z + dist kernel (v5: Z in LDS, reg-safe) =====
// grid 1024 = (B/128) x NC; c = bid&7 (XCD-pinned Wq/embT slices).
// launch_bounds(512,2): v3's proven register spec (no spill).
// Phase 1: z-GEMM K=1024, 32 tiles BK=32, 3-deep staging in [0:60KB).
// Phase 2: acc -> Z bf16 swizzled in [0:128KB); row norms plain-stored.
// Phase 3: dist vs embT[c] in TWO 256-entry passes (acc2[4][4], 64 regs);
//          embT staged 2x16KB ping-pong at [128:160KB); Z read from LDS.
__global__ __launch_bounds__(512, 2) void k_zdist(
    const ushort* __restrict__ preB, const ushort* __restrict__ WqB,
    const float* __restrict__ bq, const ushort* __restrict__ embT,
    const float* __restrict__ esq, float* __restrict__ zzG,
    unsigned long long* __restrict__ amin)
{
  __shared__ ushort smem[81920];                 // 163840 B = 160 KB
  const int tid = threadIdx.x;
  const int lane = tid & 63;
  const int w = tid >> 6;
  const int wm = w >> 2, wn = w & 3;             // 2M x 4N waves
  const int g = lane >> 4, c0 = lane & 15;
  const int bid = blockIdx.x;
  const int c = bid & 7;
  const int mBase = (bid >> 3) * 128;

  // phase-1 staging sources (pre-swizzled cols, linear LDS dest)
  const int arow = tid >> 2, aslot = tid & 3;
  const int acs = (aslot ^ (arow & 3)) * 8;
  const ushort* aSrcP = preB + (size_t)(mBase + arow)*CH_SZ + acs;
  const ushort* bSrcW[4];
  #pragma unroll
  for (int j = 0; j < 4; ++j) {
    int q = tid + j*512, br = q >> 2, bs = ((q & 3) ^ (br & 3)) * 8;
    bSrcW[j] = WqB + (size_t)(c*512 + br)*CH_SZ + bs;
  }
  // phase-3 embT staging bases: half-tile = 256 ne-rows x 32 k = 16 KB
  const int erow = (tid + 0) >> 2;               // er in [0,128) for j=0
  // per-thread 2 chunks: f = tid + j*512, er = f>>2 in [0,256)

  // ---------------- phase 1: z-GEMM (K=1024, 32 tiles, 3-deep) -----------
  f32x4 acc[4][8];
  #pragma unroll
  for (int m=0;m<4;++m)
    #pragma unroll
    for (int n=0;n<8;++n) acc[m][n] = (f32x4){0.f,0.f,0.f,0.f};

  {
    auto issue = [&](int t) {
      int kt = t * 32, b = t % 3;
      ushort* ab = smem + b*20480;
      ushort* bb = smem + b*20480 + 4096;
      gload_lds16(aSrcP + kt, ab + tid*8);
      #pragma unroll
      for (int j=0;j<4;++j) gload_lds16(bSrcW[j] + kt, bb + (tid + j*512)*8);
    };
    issue(0); issue(1);                          // 10 outstanding
    for (int t = 0; t < 32; ++t) {
      if (t < 31) { WAITV(5); } else { WAITV(0); }
      BAR();                                     // tile t visible to all
      if (t + 2 < 32) issue(t + 2);              // overwrites buf of t-1 (safe)
      const ushort* ab = smem + (t % 3)*20480;
      const ushort* bb = ab + 4096;
      short8 af[4], bf2[8];
      #pragma unroll
      for (int m=0;m<4;++m) {
        int ar = wm*64 + m*16 + c0;
        af[m] = *(const short8*)(ab + ar*32 + ((g ^ (ar & 3)) * 8));
      }
      #pragma unroll
      for (int n=0;n<8;++n) {
        int br = wn*128 + n*16 + c0;
        bf2[n] = *(const short8*)(bb + br*32 + ((g ^ (br & 3)) * 8));
      }
      SP1();
      #pragma unroll
      for (int m=0;m<4;++m)
        #pragma unroll
        for (int n=0;n<8;++n)
          acc[m][n] = __builtin_amdgcn_mfma_f32_16x16x32_bf16(af[m], bf2[n], acc[m][n], 0, 0, 0);
      SP0();
    }
    BAR();                                       // all phase-1 LDS reads done
  }

  // ---------------- phase 2: acc -> Z bf16 in LDS (swizzled) + norms -----
  #pragma unroll
  for (int m=0;m<4;++m) {
    float sq[4] = {0.f,0.f,0.f,0.f};
    #pragma unroll
    for (int n=0;n<8;++n) {
      int col = wn*128 + n*16 + c0;
      float bb = bq[c*512 + col];
      #pragma unroll
      for (int r=0;r<4;++r) {
        int row = wm*64 + m*16 + g*4 + r;
        float v = acc[m][n][r] + bb;
        ushort hb = f2bf(v);
        int byte = row*1024 + ((col*2) ^ ((row&7)<<4));
        smem[byte>>1] = hb;
        float vb = bf2f(hb);
        sq[r] += vb*vb;
      }
    }
    #pragma unroll
    for (int r=0;r<4;++r) {
      float s = sq[r];
      s += __shfl_xor(s,1); s += __shfl_xor(s,2);
      s += __shfl_xor(s,4); s += __shfl_xor(s,8);
      if (c0 == 0) {
        int row = wm*64 + m*16 + g*4 + r;
        zzG[(size_t)(mBase + row)*NC_SZ + c] = s;  // single producer: plain store
      }
    }
  }
  WAITL();                                       // drain Z ds_writes
  BAR();                                         // Z published

  // ---------------- phase 3: dist GEMM from Z-LDS, two ne-halves ---------
  float rv[4][4]; int ri[4][4];
  #pragma unroll
  for (int m=0;m<4;++m)
    #pragma unroll
    for (int r=0;r<4;++r) { rv[m][r] = 3.0e38f; ri[m][r] = 0; }

  for (int h = 0; h < 2; ++h) {
    const ushort* eS0;
    const ushort* eS1;
    {
      int f0 = tid, f1 = tid + 512;
      int er0 = f0 >> 2, es0 = ((f0 & 3) ^ (er0 & 3)) * 8;
      int er1 = f1 >> 2, es1 = ((f1 & 3) ^ (er1 & 3)) * 8;
      eS0 = embT + (size_t)(c*512 + h*256 + er0)*512 + es0;
      eS1 = embT + (size_t)(c*512 + h*256 + er1)*512 + es1;
    }
    f32x4 acc2[4][4];
    #pragma unroll
    for (int m=0;m<4;++m)
      #pragma unroll
      for (int n=0;n<4;++n) acc2[m][n] = (f32x4){0.f,0.f,0.f,0.f};

    auto issue_e = [&](int s) {
      int kt = s * 32;                           // element offset in row
      ushort* eb = smem + 65536 + (s & 1)*8192;
      gload_lds16(eS0 + kt, eb + tid*8);
      gload_lds16(eS1 + kt, eb + (tid + 512)*8);
    };
    issue_e(0); issue_e(1);                      // 4 outstanding
    for (int s = 0; s < 16; ++s) {
      if (s < 15) { WAITV(2); } else { WAITV(0); }
      BAR();                                     // stage s visible
      const ushort* eb = smem + 65536 + (s & 1)*8192;
      short8 af[4], bf2[4];
      #pragma unroll
      for (int m=0;m<4;++m) {
        int ar = wm*64 + m*16 + c0;
        af[m] = *(const short8*)(smem + ((ar*1024 + ((s*64 + g*16) ^ ((ar&7)<<4)))>>1));
      }
      #pragma unroll
      for (int n=0;n<4;++n) {
        int rbr = wn*64 + n*16 + c0;             // row within 256-half
        bf2[n] = *(const short8*)(eb + ((rbr*64 + ((g*16) ^ ((rbr&3)<<4)))>>1));
      }
      SP1();
      #pragma unroll
      for (int m=0;m<4;++m)
        #pragma unroll
        for (int n=0;n<4;++n)
          acc2[m][n] = __builtin_amdgcn_mfma_f32_16x16x32_bf16(af[m], bf2[n], acc2[m][n], 0, 0, 0);
      SP0();
      BAR();                                     // reads of buf (s&1) done
      if (s + 2 < 16) issue_e(s + 2);            // safe overwrite
    }
    // fold this half into running (min,idx)
    #pragma unroll
    for (int m=0;m<4;++m)
      #pragma unroll
      for (int n=0;n<4;++n) {
        int ne = h*256 + wn*64 + n*16 + c0;
        float ev = esq[c*512 + ne];
        #pragma unroll
        for (int r=0;r<4;++r) {
          float v = ev - 2.0f*acc2[m][n][r];
          if (v < rv[m][r]) { rv[m][r] = v; ri[m][r] = ne; }
        }
      }
  }

  // epilogue: fold across c0 lanes, publish via u64 atomicMin
  #pragma unroll
  for (int m=0;m<4;++m)
    #pragma unroll
    for (int r=0;r<4;++r) {
      float bv = rv[m][r]; int bi = ri[m][r];
      #pragma unroll
      for (int off=1; off<16; off<<=1) {
        float ov = __shfl_xor(bv, off);
        int   oi = __shfl_xor(bi, off);
        if (ov < bv || (ov == bv && oi < bi)) { bv = ov; bi = oi; }
      }
      if (c0 == 0) {
        unsigned u; { union {float f; unsigned uu;} cv; cv.f = bv; u = cv.uu; }
        unsigned k = (u & 0x80000000u) ? ~u : (u | 0x80000000u);
        unsigned long long key = (((unsigned long long)k) << 32) | (unsigned)bi;
        int row = wm*64 + m*16 + g*4 + r;
        atomicMin(&amin[(size_t)(mBase + row)*NC_SZ + c], key);
      }
    }
}

// unpack argmin winners -> counts + dacc
__global__ __launch_bounds__(256) void k_fin2(
    const unsigned long long* __restrict__ amin, const float* __restrict__ zzG,
    int* __restrict__ counts, float* __restrict__ dacc)
{
  int t = blockIdx.x*256 + threadIdx.x;          // t < B*NC
  unsigned long long key = amin[t];
  unsigned k = (unsigned)(key >> 32);
  int ne = (int)(key & 0xFFFFFFFFu);
  unsigned u = (k & 0x80000000u) ? (k ^ 0x80000000u) : ~k;
  float bv; { union {unsigned uu; float f;} cv; cv.uu = u; bv = cv.f; }
  int c = t & 7;
  atomicAdd(&counts[c*NE_SZ + ne], 1);
  float dm = bv + zzG[t];
  #pragma unroll
  for (int off=1; off<64; off<<=1) dm += __shfl_xor(dm, off);
  if ((threadIdx.x & 63) == 0) atomicAdd(dacc, dm);
}

// ===================== 256x256 GEMM core =====================
#define RD_A(P) _Pragma("unroll") for (int m=0;m<4;++m){ int ar=wm*64+m*16+c0; int sw=(ar&7)<<4; \
  _Pragma("unroll") for (int ks=0;ks<2;++ks) af[m][ks]=*(const short8*)((P)+ar*64+((((ks<<6)|gsh)^sw)>>1)); }
#define RD_B_H(H,P) _Pragma("unroll") for (int n=0;n<2;++n){ int br=wn*32+n*16+c0; int sw=(br&7)<<4; \
  _Pragma("unroll") for (int ks=0;ks<2;++ks) bfr[H][n][ks]=*(const short8*)((P)+br*64+((((ks<<6)|gsh)^sw)>>1)); }
#define MM(HA,HB) _Pragma("unroll") for (int m=0;m<4;++m) _Pragma("unroll") for (int n=0;n<2;++n){ \
  acc[HA][m][HB][n]=__builtin_amdgcn_mfma_f32_16x16x32_bf16(af[m][0],bfr[HB][n][0],acc[HA][m][HB][n],0,0,0); \
  acc[HA][m][HB][n]=__builtin_amdgcn_mfma_f32_16x16x32_bf16(af[m][1],bfr[HB][n][1],acc[HA][m][HB][n],0,0,0); }

template<int NT>
__device__ __forceinline__ void gemm256(
    const ushort* __restrict__ A, int lda, int aBase,
    const ushort* __restrict__ Bt, int ldb, int bBase,
    ushort* sA, ushort* sB, f32x4 (&acc)[2][4][2][2])
{
  const int tid = threadIdx.x;
  const int lane = tid & 63;
  const int w = tid >> 6;
  const int wm = w >> 2, wn = w & 3;
  const int g = lane >> 4, c0 = lane & 15;
  const int gsh = g << 4;

  const int f0 = tid, f1 = 512 + tid;
  const int r0 = f0 >> 3, r1 = f1 >> 3;
  const int cs0 = ((f0 & 7) ^ (r0 & 7)) * 8, cs1 = ((f1 & 7) ^ (r1 & 7)) * 8;
  const ushort* aS0 = A + (size_t)(aBase + r0)*lda + cs0;
  const ushort* aS1 = A + (size_t)(aBase + r1)*lda + cs1;
  const ushort* bS0 = Bt + (size_t)(bBase + r0)*ldb + cs0;
  const ushort* bS1 = Bt + (size_t)(bBase + r1)*ldb + cs1;
  const size_t a128 = (size_t)128*lda, b128 = (size_t)128*ldb;

  auto issue = [&](int si) {
    int tt = si >> 2, q = si & 3, kt = tt << 6, buf2 = (tt & 1) * 2;
    if (q == 0)      { ushort* d = sA +  buf2   *8192; gload_lds16(aS0 + kt,        d + f0*8); gload_lds16(aS1 + kt,        d + f1*8); }
    else if (q == 1) { ushort* d = sB +  buf2   *8192; gload_lds16(bS0 + kt,        d + f0*8); gload_lds16(bS1 + kt,        d + f1*8); }
    else if (q == 2) { ushort* d = sB + (buf2+1)*8192; gload_lds16(bS0 + b128 + kt, d + f0*8); gload_lds16(bS1 + b128 + kt, d + f1*8); }
    else             { ushort* d = sA + (buf2+1)*8192; gload_lds16(aS0 + a128 + kt, d + f0*8); gload_lds16(aS1 + a128 + kt, d + f1*8); }
  };

  #pragma unroll
  for (int hA=0;hA<2;++hA)
    #pragma unroll
    for (int m=0;m<4;++m)
      #pragma unroll
      for (int hB=0;hB<2;++hB)
        #pragma unroll
        for (int n=0;n<2;++n) acc[hA][m][hB][n] = (f32x4){0.f,0.f,0.f,0.f};

  issue(0); issue(1); issue(2); issue(3);
  WAITV(2); BAR();

  for (int t = 0; t < NT-1; ++t) {
    const int buf2 = (t & 1) * 2;
    const ushort* pA0 = sA +  buf2   *8192;
    const ushort* pA1 = sA + (buf2+1)*8192;
    const ushort* pB0 = sB +  buf2   *8192;
    const ushort* pB1 = sB + (buf2+1)*8192;
    short8 af[4][2], bfr[2][2][2];
    RD_A(pA0); RD_B_H(0,pB0); RD_B_H(1,pB1);
    issue(4*t+4);
    SP1(); MM(0,0); SP0();
    issue(4*t+5); issue(4*t+6);
    WAITV(6);
    SP1(); MM(0,1); SP0();
    BAR();
    RD_A(pA1);
    SP1(); MM(1,0); SP0();
    issue(4*t+7);
    WAITV(2);
    SP1(); MM(1,1); SP0();
    BAR();
  }
  {
    const int buf2 = ((NT-1) & 1) * 2;
    const ushort* pA0 = sA +  buf2   *8192;
    const ushort* pA1 = sA + (buf2+1)*8192;
    const ushort* pB0 = sB +  buf2   *8192;
    const ushort* pB1 = sB + (buf2+1)*8192;
    short8 af[4][2], bfr[2][2][2];
    RD_A(pA0); RD_B_H(0,pB0); RD_B_H(1,pB1);
    SP1(); MM(0,0); SP0();
    WAITV(0);
    SP1(); MM(0,1); SP0();
    BAR();
    RD_A(pA1);
    SP1(); MM(1,0); MM(1,1); SP0();
  }
}

// concat x-GEMM: pre | h1 in one GEMM (N=2048), grid 512, XCD-pinned n-slice
__global__ __launch_bounds__(512, 2) void k256_xcat(
    const ushort* __restrict__ A, const ushort* __restrict__ Wcat,
    const float* __restrict__ b_f, const float* __restrict__ b_x1,
    ushort* __restrict__ pre, ushort* __restrict__ h1)
{
  __shared__ ushort smem[65536];
  ushort* sA = smem;
  ushort* sB = smem + 32768;
  f32x4 acc[2][4][2][2];
  const int bid = blockIdx.x;
  const int nBase = (bid & 7) * 256;
  const int mBase = (bid >> 3) * 256;
  gemm256<8>(A, IN_SZ, mBase, Wcat, IN_SZ, nBase, sA, sB, acc);
  const int lane = threadIdx.x & 63, w = threadIdx.x >> 6;
  const int wm = w >> 2, wn = w & 3, g = lane >> 4, c0 = lane & 15;
  const int side = nBase >> 10;                  // 0: pre, 1: h1
  ushort* Cout = side ? h1 : pre;
  const float* bias = side ? b_x1 : b_f;
  const int obase = nBase & 1023;
  __syncthreads();
  #pragma unroll
  for (int hA=0;hA<2;++hA)
    #pragma unroll
    for (int m=0;m<4;++m)
      #pragma unroll
      for (int hB=0;hB<2;++hB)
        #pragma unroll
        for (int n=0;n<2;++n) {
          int lcol = hB*128 + wn*32 + n*16 + c0;
          float bb = bias[obase + lcol];
          #pragma unroll
          for (int r=0;r<4;++r) {
            int lrow = hA*128 + wm*64 + m*16 + g*4 + r;
            smem[lrow*256 + lcol] = f2bf(fmaxf(acc[hA][m][hB][n][r] + bb, 0.f));
          }
        }
  __syncthreads();
  #pragma unroll
  for (int p=0;p<16;++p) {
    int row = p*16 + (threadIdx.x >> 5);
    short8 v = *(const short8*)(smem + row*256 + (threadIdx.x & 31)*8);
    *(short8*)(Cout + (size_t)(mBase + row)*CH_SZ + obase + (threadIdx.x & 31)*8) = v;
  }
}

// ===================== small kernels =====================
template<int BM, int BN>
__device__ __forceinline__ void gemm_core(
    const ushort* __restrict__ A, int lda, int aBase,
    const ushort* __restrict__ Bt, int ldb, int bBase,
    int K,
    ushort (&sA)[BM][64], ushort (&sB)[BN][64],
    f32x4 (&acc)[BM/32][BN/32])
{
  constexpr int MF = BM/32, NF = BN/32;
  const int tid = threadIdx.x;
  const int lane = tid & 63;
  const int w = tid >> 6;
  const int g = lane >> 4, c0 = lane & 15;
  const int wrow = (w >> 1) * (BM/2), wcol = (w & 1) * (BN/2);

  #pragma unroll
  for (int m=0;m<MF;m++)
    #pragma unroll
    for (int n=0;n<NF;n++) acc[m][n] = (f32x4){0.f,0.f,0.f,0.f};

  for (int kt = 0; kt < K; kt += 64) {
    #pragma unroll
    for (int i = 0; i < BM/32; ++i) {
      int f = i*256 + tid;
      int r = f >> 3, cc = f & 7;
      gload_lds16(A + (size_t)(aBase + r)*lda + (kt + cc*8), &sA[r][cc*8]);
    }
    #pragma unroll
    for (int i = 0; i < BN/32; ++i) {
      int f = i*256 + tid;
      int r = f >> 3, cc = f & 7;
      gload_lds16(Bt + (size_t)(bBase + r)*ldb + (kt + cc*8), &sB[r][cc*8]);
    }
    __syncthreads();
    #pragma unroll
    for (int ks = 0; ks < 64; ks += 32) {
      short8 av[MF], bv2[NF];
      #pragma unroll
      for (int m=0;m<MF;m++)
        av[m] = *(const short8*)(&sA[wrow + m*16 + c0][ks + g*8]);
      #pragma unroll
      for (int n=0;n<NF;n++)
        bv2[n] = *(const short8*)(&sB[wcol + n*16 + c0][ks + g*8]);
      #pragma unroll
      for (int m=0;m<MF;m++)
        #pragma unroll
        for (int n=0;n<NF;n++)
          acc[m][n] = __builtin_amdgcn_mfma_f32_16x16x32_bf16(av[m], bv2[n], acc[m][n], 0, 0, 0);
    }
    __syncthreads();
  }
}

__global__ __launch_bounds__(256) void k_cvt(const float* __restrict__ s,
                                             ushort* __restrict__ d, int n) {
  int i = (blockIdx.x*256 + threadIdx.x)*4;
  if (i + 3 < n) {
    float4 v = *(const float4*)(s + i);
    ushort4 o;
    o.x = f2bf(v.x); o.y = f2bf(v.y); o.z = f2bf(v.z); o.w = f2bf(v.w);
    *(ushort4*)(d + i) = o;
  }
}

__global__ __launch_bounds__(256) void k_pad_wx2(const float* __restrict__ s,
                                                 ushort* __restrict__ d) {
  int i = blockIdx.x*256 + threadIdx.x;
  int row = i >> 10, col = i & 1023;
  d[i] = (row < 63) ? f2bf(s[row*1024 + col]) : (ushort)0;
}

__global__ void k_embT(const float* __restrict__ embed,
                       ushort* __restrict__ embT, float* __restrict__ e_sq) {
  __shared__ float t[32][33];
  int c = blockIdx.x, d0 = blockIdx.y*32, n0 = blockIdx.z*32;
  const float* src = embed + ((size_t)c*D_SZ + d0)*NE_SZ + n0;
  for (int dy = threadIdx.y; dy < 32; dy += 8)
    t[dy][threadIdx.x] = src[(size_t)dy*NE_SZ + threadIdx.x];
  __syncthreads();
  ushort* dst = embT + ((size_t)c*NE_SZ + n0)*D_SZ + d0;
  for (int ny = threadIdx.y; ny < 32; ny += 8)
    dst[(size_t)ny*D_SZ + threadIdx.x] = f2bf(t[threadIdx.x][ny]);
  if (threadIdx.y == 0) {
    float s = 0.f;
    #pragma unroll
    for (int dd = 0; dd < 32; ++dd) { float v = t[dd][threadIdx.x]; s += v*v; }
    atomicAdd(&e_sq[c*NE_SZ + n0 + threadIdx.x], s);
  }
}

__global__ __launch_bounds__(256) void k_gemm_dec(
    const ushort* __restrict__ H1, const ushort* __restrict__ Wx2b,
    const float* __restrict__ b_x2, const float* __restrict__ Wd1,
    const float* __restrict__ bd1, const float* __restrict__ Wd2,
    const float* __restrict__ bd2, float* __restrict__ dec)
{
  __shared__ ushort sA[64][64], sB[64][64];
  __shared__ float semb[64][65];
  f32x4 acc[2][2];
  int mBase = blockIdx.x*64;
  gemm_core<64,64>(H1, CH_SZ, mBase, Wx2b, CH_SZ, 0, CH_SZ, sA, sB, acc);
  int lane = threadIdx.x&63, w = threadIdx.x>>6;
  int g = lane>>4, c0 = lane&15, wrow = (w>>1)*32, wcol = (w&1)*32;
  #pragma unroll
  for (int m=0;m<2;m++)
    #pragma unroll
    for (int n=0;n<2;n++) {
      int col = wcol + n*16 + c0;
      float bb = (col < 63) ? b_x2[col] : 0.f;
      #pragma unroll
      for (int r=0;r<4;r++)
        semb[wrow + m*16 + g*4 + r][col] = acc[m][n][r] + bb;
    }
  __syncthreads();
  if (threadIdx.x < 64) {
    int lrow = threadIdx.x;
    float o = bd2[0];
    for (int j=0;j<63;++j) {
      float s = bd1[j];
      #pragma unroll 7
      for (int i=0;i<63;++i) s += semb[lrow][i]*Wd1[j*63+i];
      o += fmaxf(s, 0.f)*Wd2[j];
    }
    dec[mBase + lrow] = o;
  }
}

__global__ __launch_bounds__(256) void k_final(const int* __restrict__ counts,
                                               const float* __restrict__ dacc,
                                               float* __restrict__ out) {
  double s = 0.0;
  for (int i = threadIdx.x; i < NC_SZ*NE_SZ; i += 256) {
    double p = (double)counts[i] / (double)B_SZ;
    s -= p * log(p + 1e-10);
  }
  #pragma unroll
  for (int off=1; off<64; off<<=1) s += __shfl_xor(s, off);
  __shared__ double wsum[4];
  if ((threadIdx.x&63) == 0) wsum[threadIdx.x>>6] = s;
  __syncthreads();
  if (threadIdx.x == 0) {
    double e = wsum[0]+wsum[1]+wsum[2]+wsum[3];
    out[B_SZ]   = (float)((double)dacc[0] / ((double)B_SZ * (double)D_SZ));
    out[B_SZ+1] = (float)exp(e);
  }
}

extern "C" void kernel_launch(void* const* d_in, const int* in_sizes, int n_in,
                              void* d_out, int out_size, void* d_ws, size_t ws_size,
                              hipStream_t stream) {
  (void)in_sizes; (void)n_in; (void)out_size; (void)ws_size;
  const float* x    = (const float*)d_in[0];
  const float* W_f  = (const float*)d_in[1];
  const float* b_f  = (const float*)d_in[2];
  const float* W_x1 = (const float*)d_in[3];
  const float* b_x1 = (const float*)d_in[4];
  const float* W_x2 = (const float*)d_in[5];
  const float* b_x2 = (const float*)d_in[6];
  const float* Wq   = (const float*)d_in[7];
  const float* bq   = (const float*)d_in[8];
  const float* Wd1  = (const float*)d_in[9];
  const float* bd1  = (const float*)d_in[10];
  const float* Wd2  = (const float*)d_in[11];
  const float* bd2  = (const float*)d_in[12];
  const float* embed= (const float*)d_in[13];
  float* out = (float*)d_out;

  char* ws = (char*)d_ws;
  size_t off = 0;
  auto alloc = [&](size_t bytes) {
    void* p = ws + off; off = (off + bytes + 255) & ~(size_t)255; return p;
  };
  ushort* xb    = (ushort*)alloc((size_t)B_SZ*IN_SZ*2);
  ushort* preb  = (ushort*)alloc((size_t)B_SZ*CH_SZ*2);
  ushort* h1b   = (ushort*)alloc((size_t)B_SZ*CH_SZ*2);
  ushort* wcat  = (ushort*)alloc((size_t)2*CH_SZ*IN_SZ*2);
  ushort* wqb   = (ushort*)alloc((size_t)ED_SZ*CH_SZ*2);
  ushort* wx2b  = (ushort*)alloc((size_t)64*CH_SZ*2);
  ushort* embTb = (ushort*)alloc((size_t)NC_SZ*NE_SZ*D_SZ*2);
  float*  esq   = (float*)alloc((size_t)NC_SZ*NE_SZ*4);
  float*  zzG   = (float*)alloc((size_t)B_SZ*NC_SZ*4);
  unsigned long long* amin = (unsigned long long*)alloc((size_t)B_SZ*NC_SZ*8);
  int*    counts= (int*)alloc(4096*4);
  float*  dacc  = (float*)alloc(256);

  hipMemsetAsync(esq, 0, (size_t)NC_SZ*NE_SZ*4, stream);
  hipMemsetAsync(amin, 0xFF, (size_t)B_SZ*NC_SZ*8, stream);
  hipMemsetAsync(counts, 0, 4096*4, stream);
  hipMemsetAsync(dacc, 0, 4, stream);

  k_cvt<<<(B_SZ*IN_SZ/4+255)/256, 256, 0, stream>>>(x, xb, B_SZ*IN_SZ);
  k_cvt<<<(CH_SZ*IN_SZ/4+255)/256, 256, 0, stream>>>(W_f, wcat, CH_SZ*IN_SZ);
  k_cvt<<<(CH_SZ*IN_SZ/4+255)/256, 256, 0, stream>>>(W_x1, wcat + (size_t)CH_SZ*IN_SZ, CH_SZ*IN_SZ);
  k_cvt<<<(ED_SZ*CH_SZ/4+255)/256, 256, 0, stream>>>(Wq, wqb, ED_SZ*CH_SZ);
  k_pad_wx2<<<(64*CH_SZ)/256, 256, 0, stream>>>(W_x2, wx2b);
  k_embT<<<dim3(NC_SZ, D_SZ/32, NE_SZ/32), dim3(32,8), 0, stream>>>(embed, embTb, esq);

  // pre = relu(x@W_f^T+b_f), h1 = relu(x@W_x1^T+b_x1) in ONE GEMM (N=2048)
  k256_xcat<<<(B_SZ/256)*8, 512, 0, stream>>>(xb, wcat, b_f, b_x1, preb, h1b);
  // fused z-GEMM + dist, Z kept in LDS (no global bounce)
  k_zdist<<<(B_SZ/128)*NC_SZ, 512, 0, stream>>>(
      preb, wqb, bq, embTb, esq, zzG, amin);
  // emb = h1 @ W_x2^T + b_x2 ; dec = decoder(emb)
  k_gemm_dec<<<dim3(B_SZ/64), 256, 0, stream>>>(h1b, wx2b, b_x2, Wd1, bd1, Wd2, bd2, out);
  k_fin2<<<(B_SZ*NC_SZ)/256, 256, 0, stream>>>(amin, zzG, counts, dacc);
  k_final<<<1, 256, 0, stream>>>(counts, dacc, out);
}